// Round 1
// baseline (82.465 us; speedup 1.0000x reference)
//
#include <hip/hip_runtime.h>

#define L_RES 4096
#define EPSF 1e-8f

struct V3 { float x, y, z; };

__device__ __forceinline__ V3 v3sub(V3 a, V3 b) { return {a.x-b.x, a.y-b.y, a.z-b.z}; }
__device__ __forceinline__ V3 v3cross(V3 a, V3 b) {
    return {a.y*b.z - a.z*b.y, a.z*b.x - a.x*b.z, a.x*b.y - a.y*b.x};
}
__device__ __forceinline__ float v3dot(V3 a, V3 b) { return a.x*b.x + a.y*b.y + a.z*b.z; }

// Returns (sin(dihedral), cos(dihedral)) matching the reference:
//   angle = arccos(clip(dot(n1n,n2n))) ; dihedral = angle * sign(dot(n1n, v3))
//   sin(dihedral) = sign * sqrt(1 - c^2);  cos(dihedral) = c   (sign != 0)
//   sign == 0  ->  dihedral = 0  ->  sin = 0, cos = 1
__device__ __forceinline__ void dihedral_sc(V3 p1, V3 p2, V3 p3, V3 p4,
                                            float& s_out, float& c_out) {
    V3 v1 = v3sub(p2, p1);
    V3 v2 = v3sub(p3, p2);
    V3 v3 = v3sub(p4, p3);
    V3 n1 = v3cross(v1, v2);
    V3 n2 = v3cross(v2, v3);
    float sq1 = v3dot(n1, n1);
    float sq2 = v3dot(n2, n2);
    float nrm1 = (sq1 > 0.f) ? sqrtf(sq1) : 0.f;   // _safe_norm semantics
    float nrm2 = (sq2 > 0.f) ? sqrtf(sq2) : 0.f;
    float inv1 = 1.f / (nrm1 + EPSF);
    float inv2 = 1.f / (nrm2 + EPSF);
    float c = (n1.x*n2.x + n1.y*n2.y + n1.z*n2.z) * (inv1 * inv2);
    c = fminf(1.f, fmaxf(-1.f, c));
    float sg = (n1.x*v3.x + n1.y*v3.y + n1.z*v3.z) * inv1;  // sign(dot(n1n,v3)) == sign(this)
    float sgn = (sg > 0.f) ? 1.f : ((sg < 0.f) ? -1.f : 0.f);
    float s = sqrtf(fmaxf(0.f, (1.f - c) * (1.f + c)));
    s_out = sgn * s;
    c_out = (sg == 0.f) ? 1.f : c;   // sign==0 -> angle*sign==0 -> cos==1
}

// Block = 256 threads; each block handles 256 consecutive residues of one batch row.
// Phase 1: thread t computes the 6 encodings for residue l0+t -> LDS.
// Phase 2: thread t owns output dims [4*(t&15), +4); iterates residues; fully
//          coalesced float4 stores (consecutive tid -> consecutive addresses).
__global__ __launch_bounds__(256) void dihedral_enc_kernel(
        const float* __restrict__ coords,   // (B, L, 4, 3)
        const float* __restrict__ W,        // (64, 6) row-major
        const float* __restrict__ bias,     // (64,)
        float* __restrict__ out) {          // (B, L, 64)
    __shared__ float enc_s[256 * 7];        // stride 7: conflict-free LDS

    const int t   = threadIdx.x;
    const int blk = blockIdx.x;
    const int b   = blk >> 4;               // 16 chunks of 256 per L=4096 row
    const int l   = ((blk & 15) << 8) + t;  // residue index within row

    const long rowf = (long)b * L_RES * 12;            // float offset of row
    const long ownf = rowf + (long)l * 12;             // residue: 12 floats, 48B-aligned
    const float4* c4 = (const float4*)coords;

    // own residue: floats 0..8 = N, CA, C
    float4 a0 = c4[(ownf >> 2) + 0];
    float4 a1 = c4[(ownf >> 2) + 1];
    float  a2x = coords[ownf + 8];
    V3 N  = {a0.x, a0.y, a0.z};
    V3 CA = {a0.w, a1.x, a1.y};
    V3 C  = {a1.z, a1.w, a2x};

    // prev residue (clamped): need C = floats 6,7,8
    const int lp = (l == 0) ? 0 : (l - 1);
    const long pf = rowf + (long)lp * 12;
    float4 pv = c4[(pf >> 2) + 1];          // floats 4..7
    float  p8 = coords[pf + 8];
    V3 C_prev = {pv.z, pv.w, p8};

    // next residue (clamped): need N = floats 0..2, CA = floats 3..5
    const bool is_last = (l == L_RES - 1);
    const int ln = is_last ? l : (l + 1);
    const long nf = rowf + (long)ln * 12;
    float4 q0 = c4[(nf >> 2) + 0];
    float4 q1 = c4[(nf >> 2) + 1];
    V3 N_next  = {q0.x, q0.y, q0.z};
    V3 CA_next = {q0.w, q1.x, q1.y};

    // omega p3/p4: N[l+1], CA[l+1] for l<L-1, else CA[l] (reference concat)
    V3 om3 = is_last ? CA : N_next;
    V3 om4 = is_last ? CA : CA_next;

    float s_phi, c_phi, s_psi, c_psi, s_om, c_om;
    dihedral_sc(C_prev, N, CA, C,      s_phi, c_phi);
    dihedral_sc(N, CA, C, N_next,      s_psi, c_psi);
    dihedral_sc(CA, C, om3, om4,       s_om,  c_om);

    // encoded = [sin phi, sin psi, sin om, cos phi, cos psi, cos om]
    float* e = &enc_s[t * 7];
    e[0] = s_phi; e[1] = s_psi; e[2] = s_om;
    e[3] = c_phi; e[4] = c_psi; e[5] = c_om;

    __syncthreads();

    // Phase 2: thread owns dims d4..d4+3; W rows in registers.
    const int d4 = (t & 15) << 2;
    float w[4][6], bb[4];
    #pragma unroll
    for (int j = 0; j < 4; ++j) {
        bb[j] = bias[d4 + j];
        #pragma unroll
        for (int k = 0; k < 6; ++k) w[j][k] = W[(d4 + j) * 6 + k];
    }

    const int rg = t >> 4;                       // residue subgroup 0..15
    float4* outp = (float4*)out;
    const long ob4 = (long)blk * 4096;           // blk*256 residues * 64 dims / 4
    #pragma unroll 4
    for (int it = 0; it < 16; ++it) {
        const int r = it * 16 + rg;
        const float* er = &enc_s[r * 7];
        float e0 = er[0], e1 = er[1], e2 = er[2];
        float e3 = er[3], e4 = er[4], e5 = er[5];
        float4 o;
        o.x = fmaf(e0, w[0][0], fmaf(e1, w[0][1], fmaf(e2, w[0][2],
              fmaf(e3, w[0][3], fmaf(e4, w[0][4], fmaf(e5, w[0][5], bb[0]))))));
        o.y = fmaf(e0, w[1][0], fmaf(e1, w[1][1], fmaf(e2, w[1][2],
              fmaf(e3, w[1][3], fmaf(e4, w[1][4], fmaf(e5, w[1][5], bb[1]))))));
        o.z = fmaf(e0, w[2][0], fmaf(e1, w[2][1], fmaf(e2, w[2][2],
              fmaf(e3, w[2][3], fmaf(e4, w[2][4], fmaf(e5, w[2][5], bb[2]))))));
        o.w = fmaf(e0, w[3][0], fmaf(e1, w[3][1], fmaf(e2, w[3][2],
              fmaf(e3, w[3][3], fmaf(e4, w[3][4], fmaf(e5, w[3][5], bb[3]))))));
        outp[ob4 + it * 256 + t] = o;
    }
}

extern "C" void kernel_launch(void* const* d_in, const int* in_sizes, int n_in,
                              void* d_out, int out_size, void* d_ws, size_t ws_size,
                              hipStream_t stream) {
    const float* coords = (const float*)d_in[0];
    const float* W      = (const float*)d_in[1];
    const float* bias   = (const float*)d_in[2];
    float* out          = (float*)d_out;

    const int total_res = in_sizes[0] / 12;      // B * L
    const int blocks    = total_res / 256;       // 1024 for B=64, L=4096
    dihedral_enc_kernel<<<blocks, 256, 0, stream>>>(coords, W, bias, out);
}